// Round 1
// baseline (181.777 us; speedup 1.0000x reference)
//
#include <hip/hip_runtime.h>
#include <cmath>

// Flash attention fwd, MI355X (gfx950).
// B=2 H=16 S=2048 D=64, fp32 in/out, bf16 MFMA 16x16x32 internally.
//
// Formulation per K-tile (64 keys), per block (128 queries, one (b,h)):
//   S^T = K * Q^T           (C-layout cols = q = lane&15 -> per-lane softmax stats)
//   P   = exp2(S^T - m)     (Q pre-scaled by 0.125*log2e during staging)
//   Z^T += V^T * P^T        (accumulator cols = q -> per-lane alpha rescale)
// Verified-layout MFMA (m89/m91/m120):
//   A[m=lane&15][k=(lane>>4)*8+j], B[k=(lane>>4)*8+j][n=lane&15],
//   C/D: col=lane&15, row=(lane>>4)*4+reg.

#define S_LEN   2048
#define D_HEAD  64
#define NHEADS  16
#define TQ      128   // queries per block
#define TK      64    // keys per iteration
#define LDSTR   72    // padded LDS row stride (bf16 elems; 144 B, 16B-aligned)

typedef short bfrag8 __attribute__((ext_vector_type(8)));  // 8 bf16 (A/B frag)
typedef short bfrag4 __attribute__((ext_vector_type(4)));  // 4 bf16
typedef float f32x4  __attribute__((ext_vector_type(4)));  // C/D frag

static __device__ __forceinline__ short f2bf(float f) {
  // round-to-nearest-even fp32 -> bf16 (inputs finite; no NaN path needed)
  unsigned int u = __builtin_bit_cast(unsigned int, f);
  u = (u + 0x7fffu + ((u >> 16) & 1u)) >> 16;
  return (short)(unsigned short)u;
}

__global__ __launch_bounds__(256, 2)
void fa_fwd(const float* __restrict__ Q, const float* __restrict__ K,
            const float* __restrict__ V, float* __restrict__ Out) {
  __shared__ short Qs [TQ     * LDSTR];  // [q][d]   (scaled by 0.125*log2e)
  __shared__ short Ks [TK     * LDSTR];  // [key][d]
  __shared__ short VsT[D_HEAD * LDSTR];  // [d][key] (transposed)
  __shared__ short Ps [TQ     * LDSTR];  // [q][key]

  const int tid  = threadIdx.x;
  const int wid  = tid >> 6;
  const int lane = tid & 63;
  const int quad = lane >> 4;
  const int r    = lane & 15;
  const int qb   = 32 * wid;             // this wave's q-slice within the block

  const int bh = blockIdx.y;
  const int q0 = blockIdx.x * TQ;

  const float* Qg = Q + (size_t)bh * S_LEN * D_HEAD;
  const float* Kg = K + (size_t)bh * S_LEN * D_HEAD;
  const float* Vg = V + (size_t)bh * S_LEN * D_HEAD;

  const float qscale = 0.125f * 1.44269504088896340736f;  // 1/sqrt(64) * log2(e)

  // ---- stage Q once (fp32 -> scaled bf16) ----
#pragma unroll
  for (int i = 0; i < 8; ++i) {
    int e = (i * 256 + tid) * 4;
    int row = e >> 6, col = e & 63;
    float4 v = *(const float4*)(Qg + (size_t)(q0 + row) * D_HEAD + col);
    bfrag4 o;
    o[0] = f2bf(v.x * qscale); o[1] = f2bf(v.y * qscale);
    o[2] = f2bf(v.z * qscale); o[3] = f2bf(v.w * qscale);
    *(bfrag4*)&Qs[row * LDSTR + col] = o;
  }

  f32x4 acc[4][2];                       // Z^T: rows d = 16*mt+4*quad+reg, col q = r+16*nt+qb
#pragma unroll
  for (int mt = 0; mt < 4; ++mt)
#pragma unroll
    for (int nt = 0; nt < 2; ++nt)
      acc[mt][nt] = (f32x4){0.f, 0.f, 0.f, 0.f};

  float mrun[2] = {-INFINITY, -INFINITY};
  float lrun[2] = {0.f, 0.f};

  for (int k0 = 0; k0 < S_LEN; k0 += TK) {
    __syncthreads();  // prior-iter LDS reads done before restaging

    // ---- stage K tile [key][d] ----
#pragma unroll
    for (int i = 0; i < 4; ++i) {
      int e = (i * 256 + tid) * 4;
      int row = e >> 6, col = e & 63;
      float4 v = *(const float4*)(Kg + (size_t)(k0 + row) * D_HEAD + col);
      bfrag4 o;
      o[0] = f2bf(v.x); o[1] = f2bf(v.y); o[2] = f2bf(v.z); o[3] = f2bf(v.w);
      *(bfrag4*)&Ks[row * LDSTR + col] = o;
    }
    // ---- stage V tile transposed [d][key]: lane owns one d, 16 keys ----
    {
      const int dd = tid & 63, kg = tid >> 6;
      const float* vp = Vg + (size_t)(k0 + kg * 16) * D_HEAD + dd;
      bfrag8 a, b;
#pragma unroll
      for (int j = 0; j < 8; ++j) a[j] = f2bf(vp[(size_t)j * D_HEAD]);
#pragma unroll
      for (int j = 0; j < 8; ++j) b[j] = f2bf(vp[(size_t)(8 + j) * D_HEAD]);
      *(bfrag8*)&VsT[dd * LDSTR + kg * 16]     = a;
      *(bfrag8*)&VsT[dd * LDSTR + kg * 16 + 8] = b;
    }
    __syncthreads();

    // ---- S^T = K * Q^T : rows = keys (4 m-tiles), cols = q (2 n-tiles) ----
    f32x4 st[4][2];
#pragma unroll
    for (int mt = 0; mt < 4; ++mt)
#pragma unroll
      for (int nt = 0; nt < 2; ++nt)
        st[mt][nt] = (f32x4){0.f, 0.f, 0.f, 0.f};

#pragma unroll
    for (int ks = 0; ks < 2; ++ks) {
      bfrag8 af[4], bq[2];
#pragma unroll
      for (int mt = 0; mt < 4; ++mt)
        af[mt] = *(const bfrag8*)&Ks[(r + 16 * mt) * LDSTR + quad * 8 + 32 * ks];
#pragma unroll
      for (int nt = 0; nt < 2; ++nt)
        bq[nt] = *(const bfrag8*)&Qs[(r + qb + 16 * nt) * LDSTR + quad * 8 + 32 * ks];
#pragma unroll
      for (int mt = 0; mt < 4; ++mt)
#pragma unroll
        for (int nt = 0; nt < 2; ++nt)
          st[mt][nt] = __builtin_amdgcn_mfma_f32_16x16x32_bf16(af[mt], bq[nt], st[mt][nt], 0, 0, 0);
    }

    // ---- online softmax over this tile's 64 keys (per q = lane col) ----
#pragma unroll
    for (int nt = 0; nt < 2; ++nt) {
      float mx = st[0][nt][0];
#pragma unroll
      for (int mt = 0; mt < 4; ++mt)
#pragma unroll
        for (int j = 0; j < 4; ++j)
          mx = fmaxf(mx, st[mt][nt][j]);
      mx = fmaxf(mx, __shfl_xor(mx, 16));
      mx = fmaxf(mx, __shfl_xor(mx, 32));
      float mnew  = fmaxf(mrun[nt], mx);
      float alpha = exp2f(mrun[nt] - mnew);  // first iter: exp2(-inf)=0

      float ssum = 0.f;
#pragma unroll
      for (int mt = 0; mt < 4; ++mt) {
        bfrag4 pk;
#pragma unroll
        for (int j = 0; j < 4; ++j) {
          float p = exp2f(st[mt][nt][j] - mnew);
          ssum += p;
          pk[j] = f2bf(p);
        }
        // keys 16*mt + 4*quad + {0..3} are contiguous -> one b64 write
        *(bfrag4*)&Ps[(r + qb + 16 * nt) * LDSTR + 16 * mt + 4 * quad] = pk;
      }
      ssum += __shfl_xor(ssum, 16);
      ssum += __shfl_xor(ssum, 32);
      lrun[nt] = lrun[nt] * alpha + ssum;
      mrun[nt] = mnew;
#pragma unroll
      for (int mt = 0; mt < 4; ++mt)
#pragma unroll
        for (int j = 0; j < 4; ++j)
          acc[mt][nt][j] *= alpha;
    }
    // No barrier: Ps rows [qb, qb+32) are written and read by the same wave.

    // ---- Z^T += V^T * P^T ----
#pragma unroll
    for (int ks = 0; ks < 2; ++ks) {
      bfrag8 av[4], bp[2];
#pragma unroll
      for (int mt = 0; mt < 4; ++mt)
        av[mt] = *(const bfrag8*)&VsT[(r + 16 * mt) * LDSTR + quad * 8 + 32 * ks];
#pragma unroll
      for (int nt = 0; nt < 2; ++nt)
        bp[nt] = *(const bfrag8*)&Ps[(r + qb + 16 * nt) * LDSTR + quad * 8 + 32 * ks];
#pragma unroll
      for (int mt = 0; mt < 4; ++mt)
#pragma unroll
        for (int nt = 0; nt < 2; ++nt)
          acc[mt][nt] = __builtin_amdgcn_mfma_f32_16x16x32_bf16(av[mt], bp[nt], acc[mt][nt], 0, 0, 0);
    }
  }

  // ---- epilogue: out[b][q][h*64+d] = Z^T[d][q] / l[q] ----
  const int bb = bh >> 4, hh = bh & 15;
#pragma unroll
  for (int nt = 0; nt < 2; ++nt) {
    float inv = 1.0f / lrun[nt];
    int qg = q0 + qb + 16 * nt + r;
    float* op = Out + ((size_t)bb * S_LEN + qg) * (NHEADS * D_HEAD) + hh * D_HEAD;
#pragma unroll
    for (int mt = 0; mt < 4; ++mt)
#pragma unroll
      for (int j = 0; j < 4; ++j)
        op[16 * mt + 4 * quad + j] = acc[mt][nt][j] * inv;
  }
}

extern "C" void kernel_launch(void* const* d_in, const int* in_sizes, int n_in,
                              void* d_out, int out_size, void* d_ws, size_t ws_size,
                              hipStream_t stream) {
  const float* Q = (const float*)d_in[0];
  const float* K = (const float*)d_in[1];
  const float* V = (const float*)d_in[2];
  float* O = (float*)d_out;
  dim3 grid(S_LEN / TQ, 2 * NHEADS);  // (16 q-tiles, 32 (b,h) pairs) = 512 blocks
  fa_fwd<<<grid, 256, 0, stream>>>(Q, K, V, O);
}

// Round 2
// 169.704 us; speedup vs baseline: 1.0711x; 1.0711x over previous
//
#include <hip/hip_runtime.h>
#include <cmath>

// Flash attention fwd, MI355X (gfx950).
// B=2 H=16 S=2048 D=64, fp32 in/out, bf16 MFMA 16x16x32 internally.
//
// R2: 512-thread blocks (8 waves, 16 q per wave) -> 16 waves/CU;
//     v_cvt_pk_bf16_f32 packed conversions; raw v_exp_f32; float4 epilogue.
//
// Per K-tile (64 keys), per block (128 queries, one (b,h)):
//   S^T = K * Q^T           (C-layout cols = q = lane&15 -> per-lane softmax stats)
//   P   = exp2(S^T - m)     (Q pre-scaled by 0.125*log2e during staging)
//   Z^T += V^T * P^T        (accumulator cols = q -> per-lane alpha rescale)
// Verified-layout MFMA (m89/m91/m120):
//   A[m=lane&15][k=(lane>>4)*8+j], B[k=(lane>>4)*8+j][n=lane&15],
//   C/D: col=lane&15, row=(lane>>4)*4+reg.

#define S_LEN   2048
#define D_HEAD  64
#define NHEADS  16
#define TQ      128   // queries per block
#define TK      64    // keys per iteration
#define LDSTR   72    // padded LDS row stride (bf16 elems; 144 B, 16B-aligned)

typedef short bfrag8 __attribute__((ext_vector_type(8)));  // 8 bf16 (A/B frag)
typedef float f32x4  __attribute__((ext_vector_type(4)));  // C/D frag
typedef int   i32x2  __attribute__((ext_vector_type(2)));
typedef int   i32x4  __attribute__((ext_vector_type(4)));

static __device__ __forceinline__ short f2bf(float f) {
  // round-to-nearest-even fp32 -> bf16 (inputs finite)
  unsigned int u = __builtin_bit_cast(unsigned int, f);
  u = (u + 0x7fffu + ((u >> 16) & 1u)) >> 16;
  return (short)(unsigned short)u;
}

static __device__ __forceinline__ int pk2bf(float a, float b) {
#if __has_builtin(__builtin_amdgcn_cvt_pk_bf16_f32)
  typedef __bf16 bf16x2 __attribute__((ext_vector_type(2)));
  bf16x2 r = __builtin_amdgcn_cvt_pk_bf16_f32(a, b);
  return __builtin_bit_cast(int, r);
#else
  return (int)(unsigned short)f2bf(a) | ((int)(unsigned short)f2bf(b) << 16);
#endif
}

static __device__ __forceinline__ float fexp2(float x) {
#if __has_builtin(__builtin_amdgcn_exp2f)
  return __builtin_amdgcn_exp2f(x);   // v_exp_f32: computes 2^x, exp2(-inf)=0
#else
  return exp2f(x);
#endif
}

__global__ __launch_bounds__(512, 4)
void fa_fwd(const float* __restrict__ Q, const float* __restrict__ K,
            const float* __restrict__ V, float* __restrict__ Out) {
  __shared__ short Qs [TQ     * LDSTR];  // [q][d]   (scaled by 0.125*log2e)
  __shared__ short Ks [TK     * LDSTR];  // [key][d]
  __shared__ short VsT[D_HEAD * LDSTR];  // [d][key] (transposed)
  __shared__ short Ps [TQ     * LDSTR];  // [q][key] (per-wave private rows)

  const int tid  = threadIdx.x;
  const int wid  = tid >> 6;             // 0..7
  const int lane = tid & 63;
  const int quad = lane >> 4;
  const int r    = lane & 15;
  const int qb   = 16 * wid;             // this wave's q-slice (16 queries)

  const int bh = blockIdx.y;
  const int q0 = blockIdx.x * TQ;

  const float* Qg = Q + (size_t)bh * S_LEN * D_HEAD;
  const float* Kg = K + (size_t)bh * S_LEN * D_HEAD;
  const float* Vg = V + (size_t)bh * S_LEN * D_HEAD;

  const float qscale = 0.125f * 1.44269504088896340736f;  // 1/sqrt(64) * log2(e)

  // ---- stage Q once (fp32 -> scaled bf16), 8192 elems / 512 thr ----
#pragma unroll
  for (int i = 0; i < 4; ++i) {
    int e = (i * 512 + tid) * 4;
    int row = e >> 6, col = e & 63;
    float4 v = *(const float4*)(Qg + (size_t)(q0 + row) * D_HEAD + col);
    i32x2 w;
    w[0] = pk2bf(v.x * qscale, v.y * qscale);
    w[1] = pk2bf(v.z * qscale, v.w * qscale);
    *(i32x2*)&Qs[row * LDSTR + col] = w;
  }

  f32x4 acc[4];                          // Z^T: row d = 16*mt+4*quad+reg, col q = qb+r
#pragma unroll
  for (int mt = 0; mt < 4; ++mt)
    acc[mt] = (f32x4){0.f, 0.f, 0.f, 0.f};

  float mrun = -INFINITY;
  float lrun = 0.f;

  for (int k0 = 0; k0 < S_LEN; k0 += TK) {
    __syncthreads();  // prior-iter LDS reads done before restaging

    // ---- stage K tile [key][d]: 4096 elems / 512 thr ----
#pragma unroll
    for (int i = 0; i < 2; ++i) {
      int e = (i * 512 + tid) * 4;
      int row = e >> 6, col = e & 63;
      float4 v = *(const float4*)(Kg + (size_t)(k0 + row) * D_HEAD + col);
      i32x2 w;
      w[0] = pk2bf(v.x, v.y);
      w[1] = pk2bf(v.z, v.w);
      *(i32x2*)&Ks[row * LDSTR + col] = w;
    }
    // ---- stage V transposed [d][key]: lane owns one d, 8 keys ----
    {
      const int dd = tid & 63, kg = tid >> 6;   // kg in 0..7
      const float* vp = Vg + (size_t)(k0 + kg * 8) * D_HEAD + dd;
      float t[8];
#pragma unroll
      for (int j = 0; j < 8; ++j) t[j] = vp[(size_t)j * D_HEAD];
      i32x4 w;
#pragma unroll
      for (int j = 0; j < 4; ++j) w[j] = pk2bf(t[2 * j], t[2 * j + 1]);
      *(i32x4*)&VsT[dd * LDSTR + kg * 8] = w;
    }
    __syncthreads();

    // ---- S^T = K * Q^T : rows = keys (4 m-tiles), col = q = qb+r ----
    f32x4 st[4];
#pragma unroll
    for (int mt = 0; mt < 4; ++mt)
      st[mt] = (f32x4){0.f, 0.f, 0.f, 0.f};

#pragma unroll
    for (int ks = 0; ks < 2; ++ks) {
      bfrag8 af[4], bq;
#pragma unroll
      for (int mt = 0; mt < 4; ++mt)
        af[mt] = *(const bfrag8*)&Ks[(r + 16 * mt) * LDSTR + quad * 8 + 32 * ks];
      bq = *(const bfrag8*)&Qs[(qb + r) * LDSTR + quad * 8 + 32 * ks];
#pragma unroll
      for (int mt = 0; mt < 4; ++mt)
        st[mt] = __builtin_amdgcn_mfma_f32_16x16x32_bf16(af[mt], bq, st[mt], 0, 0, 0);
    }

    // ---- online softmax over this tile's 64 keys (q = qb+r per lane) ----
    {
      float mx = st[0][0];
#pragma unroll
      for (int mt = 0; mt < 4; ++mt)
#pragma unroll
        for (int j = 0; j < 4; ++j)
          mx = fmaxf(mx, st[mt][j]);
      mx = fmaxf(mx, __shfl_xor(mx, 16));
      mx = fmaxf(mx, __shfl_xor(mx, 32));
      float mnew  = fmaxf(mrun, mx);
      float alpha = fexp2(mrun - mnew);  // first iter: exp2(-inf)=0

      float ssum = 0.f;
#pragma unroll
      for (int mt = 0; mt < 4; ++mt) {
        float p0 = fexp2(st[mt][0] - mnew);
        float p1 = fexp2(st[mt][1] - mnew);
        float p2 = fexp2(st[mt][2] - mnew);
        float p3 = fexp2(st[mt][3] - mnew);
        ssum += (p0 + p1) + (p2 + p3);
        i32x2 w;
        w[0] = pk2bf(p0, p1);
        w[1] = pk2bf(p2, p3);
        // keys 16*mt + 4*quad + {0..3} contiguous -> one b64 write
        *(i32x2*)&Ps[(qb + r) * LDSTR + 16 * mt + 4 * quad] = w;
      }
      ssum += __shfl_xor(ssum, 16);
      ssum += __shfl_xor(ssum, 32);
      lrun = lrun * alpha + ssum;
      mrun = mnew;
#pragma unroll
      for (int mt = 0; mt < 4; ++mt)
#pragma unroll
        for (int j = 0; j < 4; ++j)
          acc[mt][j] *= alpha;
    }
    // No barrier: Ps rows [qb, qb+16) are written and read by the same wave.

    // ---- Z^T += V^T * P^T ----
#pragma unroll
    for (int ks = 0; ks < 2; ++ks) {
      bfrag8 av[4], bp;
#pragma unroll
      for (int mt = 0; mt < 4; ++mt)
        av[mt] = *(const bfrag8*)&VsT[(r + 16 * mt) * LDSTR + quad * 8 + 32 * ks];
      bp = *(const bfrag8*)&Ps[(qb + r) * LDSTR + quad * 8 + 32 * ks];
#pragma unroll
      for (int mt = 0; mt < 4; ++mt)
        acc[mt] = __builtin_amdgcn_mfma_f32_16x16x32_bf16(av[mt], bp, acc[mt], 0, 0, 0);
    }
  }

  // ---- epilogue: out[b][q][h*64+d] = Z^T[d][q] / l[q], float4 stores ----
  const int bb = bh >> 4, hh = bh & 15;
  {
    float inv = 1.0f / lrun;
    int qg = q0 + qb + r;
    float* op = Out + ((size_t)bb * S_LEN + qg) * (NHEADS * D_HEAD) + hh * D_HEAD;
#pragma unroll
    for (int mt = 0; mt < 4; ++mt) {
      float4 o;
      o.x = acc[mt][0] * inv; o.y = acc[mt][1] * inv;
      o.z = acc[mt][2] * inv; o.w = acc[mt][3] * inv;
      *(float4*)(op + 16 * mt + 4 * quad) = o;
    }
  }
}

extern "C" void kernel_launch(void* const* d_in, const int* in_sizes, int n_in,
                              void* d_out, int out_size, void* d_ws, size_t ws_size,
                              hipStream_t stream) {
  const float* Q = (const float*)d_in[0];
  const float* K = (const float*)d_in[1];
  const float* V = (const float*)d_in[2];
  float* O = (float*)d_out;
  dim3 grid(S_LEN / TQ, 2 * NHEADS);  // (16 q-tiles, 32 (b,h)) = 512 blocks, 2/CU
  fa_fwd<<<grid, 512, 0, stream>>>(Q, K, V, O);
}